// Round 8
// baseline (260.117 us; speedup 1.0000x reference)
//
#include <hip/hip_runtime.h>
#include <hip/hip_bf16.h>

#define C_OUT 96
#define FEAT_DIM 48
#define HW 256
#define NPIX 65536          // 256*256
#define RES 65536           // rows in fa
#define IMG_C 3
#define NKX 8               // x-slices per window (slice = 8192 rows = 786 KB)
#define NKY 8
#define NKEY_W (NKX * NKY)  // 64 buckets per window
#define NWIN 2
#define NKEY (NKEY_W * NWIN)
#define SCAT_PPT 8

typedef __attribute__((ext_vector_type(2))) float f32x2;
typedef __attribute__((ext_vector_type(4))) float f32x4;
typedef __attribute__((ext_vector_type(8))) unsigned short u16x8;
typedef __attribute__((ext_vector_type(4))) unsigned short u16x4;

static __device__ __forceinline__ unsigned short f2bf(float f) {
    unsigned u = __float_as_uint(f);
    u += 0x7fffu + ((u >> 16) & 1u);
    return (unsigned short)(u >> 16);
}
static __device__ __forceinline__ float bf2f(unsigned short h) {
    return __uint_as_float(((unsigned)h) << 16);
}
// reference: clip(p*(res-1), 0, res-1-1e-5); hi bound rounds to 65535.0f
static __device__ __forceinline__ float clipcoord(float p) {
    return fminf(fmaxf(p * 65535.0f, 0.0f), 65535.0f);
}
static __device__ __forceinline__ int bucket_of(float x, float y) {
    return (((int)x >> 13) << 3) | ((int)y >> 13);   // kx*8 + ky
}

// ---------------------------------------------------------------------------
// Stage 1: 3x3 SAME conv -> bf16 split tables FX/FY.
// ---------------------------------------------------------------------------
__global__ __launch_bounds__(256) void conv_kernel(
    const float* __restrict__ img, const float* __restrict__ w,
    const float* __restrict__ b,
    unsigned short* __restrict__ FX, unsigned short* __restrict__ FY)
{
    __shared__ float ws[C_OUT * 27];
    __shared__ float bs[C_OUT];
    for (int i = threadIdx.x; i < C_OUT * 27; i += blockDim.x) ws[i] = w[i];
    for (int i = threadIdx.x; i < C_OUT; i += blockDim.x) bs[i] = b[i];
    __syncthreads();

    int tid = blockIdx.x * blockDim.x + threadIdx.x;
    if (tid >= (C_OUT * NPIX) / 4) return;
    int f = tid << 2;
    int c  = f >> 16;
    int p  = f & 65535;
    int h  = p >> 8;
    int wc = p & 255;

    float a0 = bs[c], a1 = a0, a2 = a0, a3 = a0;
#pragma unroll
    for (int ci = 0; ci < IMG_C; ++ci) {
        const float* ip = img + ci * NPIX;
#pragma unroll
        for (int kh = 0; kh < 3; ++kh) {
            int hh = h + kh - 1;
            if ((unsigned)hh >= 256u) continue;
            const float* row = ip + hh * HW;
            float win[6];
#pragma unroll
            for (int k = 0; k < 6; ++k) {
                int ww = wc + k - 1;
                win[k] = ((unsigned)ww < 256u) ? row[ww] : 0.0f;
            }
            const float* wk = &ws[c * 27 + ci * 9 + kh * 3];
#pragma unroll
            for (int kw = 0; kw < 3; ++kw) {
                float wt = wk[kw];
                a0 = fmaf(win[kw + 0], wt, a0);
                a1 = fmaf(win[kw + 1], wt, a1);
                a2 = fmaf(win[kw + 2], wt, a2);
                a3 = fmaf(win[kw + 3], wt, a3);
            }
        }
    }

    int r = (unsigned)f / 96u;
    int j = f - r * 96;
    u16x4 pk;
    pk.x = f2bf(a0); pk.y = f2bf(a1); pk.z = f2bf(a2); pk.w = f2bf(a3);
    unsigned short* dst = (j < FEAT_DIM)
        ? (FX + (size_t)r * FEAT_DIM + j)
        : (FY + (size_t)r * FEAT_DIM + (j - FEAT_DIM));
    *(u16x4*)dst = pk;
}

// ---------------------------------------------------------------------------
// Sort A: histogram of 128 keys (window*64 + bucket).
// ---------------------------------------------------------------------------
__global__ __launch_bounds__(256) void hist_kernel(
    const float* __restrict__ pts, unsigned* __restrict__ hist,
    int npts, int wsize)
{
    __shared__ unsigned lh[NKEY];
    for (int i = threadIdx.x; i < NKEY; i += blockDim.x) lh[i] = 0;
    __syncthreads();
    int stride = gridDim.x * blockDim.x;
    for (int i = blockIdx.x * blockDim.x + threadIdx.x; i < npts; i += stride) {
        f32x2 p = *((const f32x2*)pts + i);
        int key = (i / wsize) * NKEY_W + bucket_of(clipcoord(p.x), clipcoord(p.y));
        atomicAdd(&lh[key], 1u);
    }
    __syncthreads();
    for (int i = threadIdx.x; i < NKEY; i += blockDim.x)
        if (lh[i]) atomicAdd(&hist[i], lh[i]);
}

// ---------------------------------------------------------------------------
// Sort B: exclusive scan of 128 keys (single block).
// ---------------------------------------------------------------------------
__global__ __launch_bounds__(256) void scan_kernel(
    const unsigned* __restrict__ hist, unsigned* __restrict__ cursor)
{
    __shared__ unsigned tmp[NKEY];
    int t = threadIdx.x;
    unsigned own = 0;
    if (t < NKEY) { own = hist[t]; tmp[t] = own; }
    __syncthreads();
#pragma unroll
    for (int off = 1; off < NKEY; off <<= 1) {
        unsigned v = 0;
        if (t < NKEY && t >= off) v = tmp[t - off];
        __syncthreads();
        if (t < NKEY) tmp[t] += v;
        __syncthreads();
    }
    if (t < NKEY) cursor[t] = tmp[t] - own;
}

// ---------------------------------------------------------------------------
// Sort C: scatter {x,y,idx} records into key-sorted array.
// ---------------------------------------------------------------------------
__global__ __launch_bounds__(256) void scatter_kernel(
    const float* __restrict__ pts, unsigned* __restrict__ cursor,
    f32x4* __restrict__ sorted, int npts, int wsize)
{
    __shared__ unsigned lh[NKEY];
    __shared__ unsigned lbase[NKEY];
    int t = threadIdx.x;
    for (int i = t; i < NKEY; i += blockDim.x) lh[i] = 0;
    __syncthreads();

    int start = blockIdx.x * (blockDim.x * SCAT_PPT);
    float xs[SCAT_PPT], ys[SCAT_PPT];
    int keys[SCAT_PPT];
#pragma unroll
    for (int k = 0; k < SCAT_PPT; ++k) {
        int i = start + k * blockDim.x + t;
        if (i < npts) {
            f32x2 p = *((const f32x2*)pts + i);
            xs[k] = clipcoord(p.x);
            ys[k] = clipcoord(p.y);
            keys[k] = (i / wsize) * NKEY_W + bucket_of(xs[k], ys[k]);
            atomicAdd(&lh[keys[k]], 1u);
        } else keys[k] = -1;
    }
    __syncthreads();
    for (int i = t; i < NKEY; i += blockDim.x)
        lbase[i] = lh[i] ? atomicAdd(&cursor[i], lh[i]) : 0u;
    __syncthreads();
    for (int i = t; i < NKEY; i += blockDim.x) lh[i] = 0;
    __syncthreads();
#pragma unroll
    for (int k = 0; k < SCAT_PPT; ++k) {
        if (keys[k] >= 0) {
            unsigned slot = lbase[keys[k]] + atomicAdd(&lh[keys[k]], 1u);
            int i = start + k * blockDim.x + t;
            f32x4 rec;
            rec.x = xs[k]; rec.y = ys[k];
            rec.z = __uint_as_float((unsigned)i); rec.w = 0.0f;
            sorted[slot] = rec;
        }
    }
}

// ---------------------------------------------------------------------------
// Stage 2: interp over one WINDOW of bucket-sorted points. Launched once per
// window (sequential on stream) so the active write span is one window's
// 192 MB < L3 -> scattered 192B writes merge to full lines in shared L3.
// m204 XCD-chunk swizzle: each XCD walks a contiguous sorted range, so its
// instantaneous read working set is one 786KB FX slice + one 786KB FY slice
// (L2-resident). 6 lanes/point, u16x8 row loads, plain f32x4 stores.
// ---------------------------------------------------------------------------
__global__ __launch_bounds__(256) void interp_kernel(
    const f32x4* __restrict__ sorted,
    const unsigned short* __restrict__ FX,
    const unsigned short* __restrict__ FY,
    float* __restrict__ out, int base, int count, int nblk)
{
    int orig = blockIdx.x;
    int xcd = orig & 7;
    int q8 = nblk >> 3, r8 = nblk & 7;
    int cbase = (xcd < r8) ? xcd * (q8 + 1) : r8 * (q8 + 1) + (xcd - r8) * q8;
    int sbid = cbase + (orig >> 3);

    int t = sbid * blockDim.x + threadIdx.x;
    int s = t / 6;
    int q = t - s * 6;
    if (s >= count) return;

    f32x4 rec = sorted[base + s];
    float x = rec.x, y = rec.y;
    unsigned idx = __float_as_uint(rec.z);

    int x1 = (int)x;
    int y1 = (int)y;
    int x2 = min(x1 + 1, RES - 1);
    int y2 = min(y1 + 1, RES - 1);

    float xw1 = (float)x2 - x;
    float xw2 = x - (float)x1;
    float yw1 = (float)y2 - y;
    float yw2 = y - (float)y1;

    int qo = q * 8;
    const u16x8 A = *(const u16x8*)(FX + (size_t)x1 * FEAT_DIM + qo);
    const u16x8 B = *(const u16x8*)(FX + (size_t)x2 * FEAT_DIM + qo);
    const u16x8 C = *(const u16x8*)(FY + (size_t)y1 * FEAT_DIM + qo);
    const u16x8 D = *(const u16x8*)(FY + (size_t)y2 * FEAT_DIM + qo);

    float o[8];
#pragma unroll
    for (int k = 0; k < 8; ++k) {
        o[k] = xw1 * bf2f(A[k]) + xw2 * bf2f(B[k])
             + yw1 * bf2f(C[k]) + yw2 * bf2f(D[k]);
    }

    float* op = out + (size_t)idx * FEAT_DIM + qo;
    f32x4 v0 = {o[0], o[1], o[2], o[3]};
    f32x4 v1 = {o[4], o[5], o[6], o[7]};
    *(f32x4*)op = v0;
    *(f32x4*)(op + 4) = v1;
}

extern "C" void kernel_launch(void* const* d_in, const int* in_sizes, int n_in,
                              void* d_out, int out_size, void* d_ws, size_t ws_size,
                              hipStream_t stream) {
    const float* pts    = (const float*)d_in[0];
    const float* image  = (const float*)d_in[1];
    const float* conv_w = (const float*)d_in[2];
    const float* conv_b = (const float*)d_in[3];
    float* out = (float*)d_out;

    int npts = in_sizes[0] / 2;
    int wsize = (npts + NWIN - 1) / NWIN;     // points per window

    // ws: sorted (npts*16B) | FX (6.29MB) | FY (6.29MB) | hist | cursor
    char* wsb = (char*)d_ws;
    f32x4* sorted = (f32x4*)wsb;
    size_t sorted_bytes = ((size_t)npts * 16 + 255) & ~(size_t)255;
    unsigned short* FX = (unsigned short*)(wsb + sorted_bytes);
    unsigned short* FY = FX + (size_t)RES * FEAT_DIM;
    unsigned* hist   = (unsigned*)(wsb + sorted_bytes + 2 * (size_t)RES * FEAT_DIM * 2);
    unsigned* cursor = hist + NKEY;

    hipMemsetAsync(hist, 0, NKEY * sizeof(unsigned), stream);

    {
        int total = (C_OUT * NPIX) / 4;
        conv_kernel<<<(total + 255) / 256, 256, 0, stream>>>(image, conv_w, conv_b, FX, FY);
    }
    hist_kernel<<<1024, 256, 0, stream>>>(pts, hist, npts, wsize);
    scan_kernel<<<1, 256, 0, stream>>>(hist, cursor);
    {
        int per_block = 256 * SCAT_PPT;
        int blocks = (npts + per_block - 1) / per_block;
        scatter_kernel<<<blocks, 256, 0, stream>>>(pts, cursor, sorted, npts, wsize);
    }
    // one interp launch per window (sequential -> bounded write span)
    for (int wdx = 0; wdx < NWIN; ++wdx) {
        int base = wdx * wsize;
        int count = (base < npts) ? min(wsize, npts - base) : 0;
        if (count <= 0) break;
        long long lanes = (long long)count * 6;
        int nblk = (int)((lanes + 255) / 256);
        interp_kernel<<<nblk, 256, 0, stream>>>(sorted, FX, FY, out, base, count, nblk);
    }
}

// Round 9
// 243.352 us; speedup vs baseline: 1.0689x; 1.0689x over previous
//
#include <hip/hip_runtime.h>
#include <hip/hip_bf16.h>

#define C_OUT 96
#define FEAT_DIM 48
#define HW 256
#define NPIX 65536          // 256*256
#define RES 65536           // rows in fa
#define IMG_C 3

typedef __attribute__((ext_vector_type(2))) float f32x2;
typedef __attribute__((ext_vector_type(4))) float f32x4;
typedef __attribute__((ext_vector_type(8))) unsigned short u16x8;
typedef __attribute__((ext_vector_type(4))) unsigned short u16x4;
typedef __attribute__((ext_vector_type(16))) signed char i8x16;

static __device__ __forceinline__ unsigned short f2bf(float f) {
    // round-to-nearest-even f32 -> bf16
    unsigned u = __float_as_uint(f);
    u += 0x7fffu + ((u >> 16) & 1u);
    return (unsigned short)(u >> 16);
}
static __device__ __forceinline__ float bf2f(unsigned short h) {
    return __uint_as_float(((unsigned)h) << 16);
}

// ---------------------------------------------------------------------------
// Stage 1: 3x3 SAME conv -> bf16 staging tables FX/FY (proven R2 kernel).
// ---------------------------------------------------------------------------
__global__ __launch_bounds__(256) void conv_kernel(
    const float* __restrict__ img,          // [3,256,256]
    const float* __restrict__ w,            // [96,3,3,3]
    const float* __restrict__ b,            // [96]
    unsigned short* __restrict__ FX,        // [65536,48] bf16
    unsigned short* __restrict__ FY)        // [65536,48] bf16
{
    __shared__ float ws[C_OUT * 27];
    __shared__ float bs[C_OUT];
    for (int i = threadIdx.x; i < C_OUT * 27; i += blockDim.x) ws[i] = w[i];
    for (int i = threadIdx.x; i < C_OUT; i += blockDim.x) bs[i] = b[i];
    __syncthreads();

    int tid = blockIdx.x * blockDim.x + threadIdx.x;
    if (tid >= (C_OUT * NPIX) / 4) return;
    int f = tid << 2;
    int c  = f >> 16;
    int p  = f & 65535;
    int h  = p >> 8;
    int wc = p & 255;

    float a0 = bs[c], a1 = a0, a2 = a0, a3 = a0;
#pragma unroll
    for (int ci = 0; ci < IMG_C; ++ci) {
        const float* ip = img + ci * NPIX;
#pragma unroll
        for (int kh = 0; kh < 3; ++kh) {
            int hh = h + kh - 1;
            if ((unsigned)hh >= 256u) continue;
            const float* row = ip + hh * HW;
            float win[6];
#pragma unroll
            for (int k = 0; k < 6; ++k) {
                int ww = wc + k - 1;
                win[k] = ((unsigned)ww < 256u) ? row[ww] : 0.0f;
            }
            const float* wk = &ws[c * 27 + ci * 9 + kh * 3];
#pragma unroll
            for (int kw = 0; kw < 3; ++kw) {
                float wt = wk[kw];
                a0 = fmaf(win[kw + 0], wt, a0);
                a1 = fmaf(win[kw + 1], wt, a1);
                a2 = fmaf(win[kw + 2], wt, a2);
                a3 = fmaf(win[kw + 3], wt, a3);
            }
        }
    }

    int r = (unsigned)f / 96u;
    int j = f - r * 96;
    u16x4 pk;
    pk.x = f2bf(a0); pk.y = f2bf(a1); pk.z = f2bf(a2); pk.w = f2bf(a3);
    unsigned short* dst = (j < FEAT_DIM)
        ? (FX + (size_t)r * FEAT_DIM + j)
        : (FY + (size_t)r * FEAT_DIM + (j - FEAT_DIM));
    *(u16x4*)dst = pk;
}

// ---------------------------------------------------------------------------
// Stage 1b: per-row absmax int8 quantization. One thread per row:
// read 48 bf16 (96 B), compute rowmax, write 48 int8 (3x16B) + f32 scale.
// err/elem <= rowmax/254.
// ---------------------------------------------------------------------------
__global__ __launch_bounds__(256) void quant_kernel(
    const unsigned short* __restrict__ F,   // [65536,48] bf16
    signed char* __restrict__ Q,            // [65536,48] int8
    float* __restrict__ S,                  // [65536] f32 scale
    int nrows)
{
    int r = blockIdx.x * blockDim.x + threadIdx.x;
    if (r >= nrows) return;
    const u16x8* row = (const u16x8*)(F + (size_t)r * FEAT_DIM);

    float v[48];
    float m = 0.0f;
#pragma unroll
    for (int i = 0; i < 6; ++i) {
        u16x8 h = row[i];
#pragma unroll
        for (int k = 0; k < 8; ++k) {
            float f = bf2f(h[k]);
            v[i * 8 + k] = f;
            m = fmaxf(m, fabsf(f));
        }
    }
    float inv = (m > 0.0f) ? 127.0f / m : 0.0f;
    float s   = m * (1.0f / 127.0f);

    i8x16 o0, o1, o2;
#pragma unroll
    for (int k = 0; k < 16; ++k) o0[k] = (signed char)(int)rintf(v[k] * inv);
#pragma unroll
    for (int k = 0; k < 16; ++k) o1[k] = (signed char)(int)rintf(v[16 + k] * inv);
#pragma unroll
    for (int k = 0; k < 16; ++k) o2[k] = (signed char)(int)rintf(v[32 + k] * inv);

    i8x16* qp = (i8x16*)(Q + (size_t)r * FEAT_DIM);
    qp[0] = o0; qp[1] = o1; qp[2] = o2;
    S[r] = s;
}

// ---------------------------------------------------------------------------
// Stage 2: dual 1-D interpolation gather from int8 per-row-scaled tables.
// 3 lanes per point; lane q owns 16 features: one 16B int8 load from each of
// the 4 gathered rows (48B rows -> x-pair span is 96B contiguous), scales
// folded into the interp weights, 64B contiguous f32 output per lane.
// Sequential writes in original point order (sorting refuted R6/R8).
// ---------------------------------------------------------------------------
__global__ __launch_bounds__(256) void interp_kernel(
    const float* __restrict__ pts,            // [N,2]
    const signed char* __restrict__ QX,       // [65536,48] int8
    const signed char* __restrict__ QY,       // [65536,48] int8
    const float* __restrict__ SX,             // [65536]
    const float* __restrict__ SY,             // [65536]
    float* __restrict__ out,                  // [N,48] f32
    int npts)
{
    int t = blockIdx.x * blockDim.x + threadIdx.x;
    int pt = t / 3;
    int q  = t - pt * 3;          // 16-feature chunk: 0..2
    if (pt >= npts) return;

    f32x2 p = __builtin_nontemporal_load((const f32x2*)pts + pt);

    // reference: clip(p*(res-1), 0, res-1-1e-5); hi bound == 65535.0f in f32
    float x = fminf(fmaxf(p.x * 65535.0f, 0.0f), 65535.0f);
    float y = fminf(fmaxf(p.y * 65535.0f, 0.0f), 65535.0f);

    int x1 = (int)x;
    int y1 = (int)y;
    int x2 = min(x1 + 1, RES - 1);
    int y2 = min(y1 + 1, RES - 1);

    float xw1 = (float)x2 - x;
    float xw2 = x - (float)x1;
    float yw1 = (float)y2 - y;
    float yw2 = y - (float)y1;

    int qo = q * 16;
    // 4 independent 16B gathers + 4 hot scale loads
    const i8x16 A = *(const i8x16*)(QX + (size_t)x1 * FEAT_DIM + qo);
    const i8x16 B = *(const i8x16*)(QX + (size_t)x2 * FEAT_DIM + qo);
    const i8x16 C = *(const i8x16*)(QY + (size_t)y1 * FEAT_DIM + qo);
    const i8x16 D = *(const i8x16*)(QY + (size_t)y2 * FEAT_DIM + qo);
    float wa = xw1 * SX[x1];
    float wb = xw2 * SX[x2];
    float wc = yw1 * SY[y1];
    float wd = yw2 * SY[y2];

    float o[16];
#pragma unroll
    for (int k = 0; k < 16; ++k) {
        o[k] = wa * (float)A[k] + wb * (float)B[k]
             + wc * (float)C[k] + wd * (float)D[k];
    }

    float* op = out + (size_t)pt * FEAT_DIM + qo;
    f32x4 v0 = {o[0],  o[1],  o[2],  o[3]};
    f32x4 v1 = {o[4],  o[5],  o[6],  o[7]};
    f32x4 v2 = {o[8],  o[9],  o[10], o[11]};
    f32x4 v3 = {o[12], o[13], o[14], o[15]};
    *(f32x4*)op = v0;
    *(f32x4*)(op + 4)  = v1;
    *(f32x4*)(op + 8)  = v2;
    *(f32x4*)(op + 12) = v3;
}

extern "C" void kernel_launch(void* const* d_in, const int* in_sizes, int n_in,
                              void* d_out, int out_size, void* d_ws, size_t ws_size,
                              hipStream_t stream) {
    const float* pts    = (const float*)d_in[0];  // [N,2]
    const float* image  = (const float*)d_in[1];  // [1,3,256,256]
    const float* conv_w = (const float*)d_in[2];  // [96,3,3,3]
    const float* conv_b = (const float*)d_in[3];  // [96]
    float* out = (float*)d_out;                   // [N,48]

    // ws: FXbf16 (6.29MB) | FYbf16 (6.29MB) | QX (3.1MB) | QY (3.1MB) | SX | SY
    char* wsb = (char*)d_ws;
    unsigned short* FX = (unsigned short*)wsb;
    unsigned short* FY = FX + (size_t)RES * FEAT_DIM;
    signed char* QX = (signed char*)(wsb + 2 * (size_t)RES * FEAT_DIM * 2);
    signed char* QY = QX + (size_t)RES * FEAT_DIM;
    float* SX = (float*)(QY + (size_t)RES * FEAT_DIM);
    float* SY = SX + RES;

    int npts = in_sizes[0] / 2;

    {
        int total = (C_OUT * NPIX) / 4;
        conv_kernel<<<(total + 255) / 256, 256, 0, stream>>>(image, conv_w, conv_b, FX, FY);
    }
    quant_kernel<<<RES / 256, 256, 0, stream>>>(FX, QX, SX, RES);
    quant_kernel<<<RES / 256, 256, 0, stream>>>(FY, QY, SY, RES);
    {
        long long total = (long long)npts * 3;
        int blocks = (int)((total + 255) / 256);
        interp_kernel<<<blocks, 256, 0, stream>>>(pts, QX, QY, SX, SY, out, npts);
    }
}